// Round 19
// baseline (117.447 us; speedup 1.0000x reference)
//
#include <hip/hip_runtime.h>
#include <cmath>

// x,y: (16,3,512,512) f32. Fused separable-Gaussian SSIM, scalar mean output.
// Phase-merged pipeline: 2-row rounds, TWO 10KB LDS buffers (40KB total,
// 4 blocks/CU). Each barrier segment runs hpass(buf cur) AND vconv(next pair
// -> buf other) together, so h-pass ds_reads hide under v-conv VALU instead of
// phase-locking the LDS pipe. Static 18-slot row registers (no ring shifts),
// 2-row prefetch at segment top, XOR bank swizzle, XCD block swizzle, rcp div.
constexpr int IMG_H = 512;
constexpr int IMG_W = 512;
constexpr int PLANES = 48;
constexpr int R_OUT = 8;                 // output rows per block (4 pairs)
constexpr int BANDS = IMG_H / R_OUT;     // 64
constexpr int PSTR = 512;                // field-row dwords; col c at dword c
constexpr int BSTR = 2 * 5 * PSTR;       // one buffer: 2 rows x 5 fields
constexpr int NSLOT = 64;                // global accumulator slots (64B apart)
constexpr int NBLK = PLANES * BANDS;     // 3072 (divisible by 8 XCDs)
constexpr long long TOTAL_PIX = (long long)PLANES * IMG_H * IMG_W;

struct GWin { float g[11]; };

// XOR bank swizzle on within-field-row dword offset (bits 2..4 ^= bits 5..7).
__device__ __forceinline__ int swzd(int d) { return d ^ (((d >> 5) & 7) << 2); }
__device__ __forceinline__ int swzd4(int b) { return b ^ ((b >> 3) & 7); }

template<bool CHK>
__device__ __forceinline__ float2 ld2(const float* __restrict__ base, int gr, int c0) {
    if (CHK && (unsigned)gr >= (unsigned)IMG_H) return make_float2(0.f, 0.f);
    return *(const float2*)(base + (size_t)gr * IMG_W + c0);
}

// horizontal 11-tap conv + SSIM over one 2-row buffer (layout [5][2][PSTR]),
// 4 cols per lane; row = tid>>7, l = tid&127. Verified edge logic (R18).
__device__ __forceinline__ float hpass2(const float* __restrict__ buf,
                                        int row, int l, const int (&pb)[5],
                                        const GWin& win) {
    float m[5][4];
#pragma unroll
    for (int f = 0; f < 5; ++f) {
        const float* fr = buf + (f * 2 + row) * PSTR;
        float w20[20];
#pragma unroll
        for (int B = 0; B < 5; ++B) {
            const float4 v = *(const float4*)&fr[pb[B]];
            w20[4 * B + 0] = v.x;  w20[4 * B + 1] = v.y;
            w20[4 * B + 2] = v.z;  w20[4 * B + 3] = v.w;
        }
        if (l == 0)   { w20[3] = w20[4] = w20[5] = w20[6] = w20[7] = 0.f; }
        if (l == 1)   { w20[3] = 0.f; }
        if (l == 126) { w20[16] = 0.f; }
        if (l == 127) { w20[12] = w20[13] = w20[14] = w20[15] = w20[16] = 0.f; }
        // output col c = 4l+j: window cols c-5..c+5 -> w20[j+3+k], k=0..10
#pragma unroll
        for (int j = 0; j < 4; ++j) {
            float s = 0.f;
#pragma unroll
            for (int k = 0; k < 11; ++k) s += win.g[k] * w20[j + 3 + k];
            m[f][j] = s;
        }
    }
    float ls = 0.f;
#pragma unroll
    for (int u = 0; u < 4; ++u) {
        const float mx  = m[0][u], my  = m[1][u];
        const float mxx = m[2][u], myy = m[3][u], mxy = m[4][u];
        const float mu_x_sq = mx * mx;
        const float mu_y_sq = my * my;
        const float mu_xy   = mx * my;
        const float sig_x  = mxx - mu_x_sq;
        const float sig_y  = myy - mu_y_sq;
        const float sig_xy = mxy - mu_xy;
        const float C1 = 0.01f * 0.01f;
        const float C2 = 0.03f * 0.03f;
        const float n = (2.f * mu_xy + C1) * (2.f * sig_xy + C2);
        const float d = (mu_x_sq + mu_y_sq + C1) * (sig_x + sig_y + C2);
        ls += n * __builtin_amdgcn_rcpf(d + 1e-8f);   // ~1 ulp; mean-safe
    }
    return ls;
}

// vertical 11-tap conv of 2 rows from resident register rows I0..I0+11;
// dual-accumulate (tap k -> row0, tap k-1 -> row1); write to buffer hb.
template<int I0>
__device__ __forceinline__ void vconv2(const float2 (&xr)[18], const float2 (&yr)[18],
                                       float* __restrict__ hb, int pws,
                                       const GWin& win) {
    float2 acc[2][5];
#pragma unroll
    for (int j = 0; j < 2; ++j)
#pragma unroll
        for (int f = 0; f < 5; ++f) acc[j][f] = make_float2(0.f, 0.f);
#pragma unroll
    for (int k = 0; k < 12; ++k) {
        const float2 xv = xr[I0 + k], yv = yr[I0 + k];
        const float2 pxx = make_float2(xv.x * xv.x, xv.y * xv.y);
        const float2 pyy = make_float2(yv.x * yv.x, yv.y * yv.y);
        const float2 pxy = make_float2(xv.x * yv.x, xv.y * yv.y);
        if (k < 11) {
            const float g = win.g[k];
            acc[0][0].x += g * xv.x;   acc[0][0].y += g * xv.y;
            acc[0][1].x += g * yv.x;   acc[0][1].y += g * yv.y;
            acc[0][2].x += g * pxx.x;  acc[0][2].y += g * pxx.y;
            acc[0][3].x += g * pyy.x;  acc[0][3].y += g * pyy.y;
            acc[0][4].x += g * pxy.x;  acc[0][4].y += g * pxy.y;
        }
        if (k > 0) {
            const float g = win.g[k - 1];
            acc[1][0].x += g * xv.x;   acc[1][0].y += g * xv.y;
            acc[1][1].x += g * yv.x;   acc[1][1].y += g * yv.y;
            acc[1][2].x += g * pxx.x;  acc[1][2].y += g * pxx.y;
            acc[1][3].x += g * pyy.x;  acc[1][3].y += g * pyy.y;
            acc[1][4].x += g * pxy.x;  acc[1][4].y += g * pxy.y;
        }
    }
#pragma unroll
    for (int j = 0; j < 2; ++j)
#pragma unroll
        for (int f = 0; f < 5; ++f)
            *(float2*)&hb[(f * 2 + j) * PSTR + pws] = acc[j][f];
}

template<bool CHK>
__device__ __forceinline__ float band_body(const float* __restrict__ xp,
                                           const float* __restrict__ yp,
                                           int r0, int c0, int tid,
                                           float* __restrict__ hA,   // buffer 0
                                           const GWin& win)
{
    float* hB = hA + BSTR;               // buffer 1 (statically disjoint)
    const int pws = swzd(2 * tid);
    const int row = tid >> 7, l = tid & 127;
    int pb[5];
#pragma unroll
    for (int B = 0; B < 5; ++B) {        // hoisted h-read addresses (clamped)
        int blk = l - 2 + B;
        blk = blk < 0 ? 0 : (blk > 127 ? 127 : blk);
        pb[B] = 4 * swzd4(blk);
    }

    // rows i=0..17 <-> image rows r0-5+i; slots are static for the whole band
    float2 xr[18], yr[18];
#pragma unroll
    for (int i = 0; i < 12; ++i) {
        xr[i] = ld2<CHK>(xp, r0 - 5 + i, c0);
        yr[i] = ld2<CHK>(yp, r0 - 5 + i, c0);
    }
    // prefetch rows 12,13 (used by round 0's vconv<2>)
    xr[12] = ld2<CHK>(xp, r0 + 7, c0);  yr[12] = ld2<CHK>(yp, r0 + 7, c0);
    xr[13] = ld2<CHK>(xp, r0 + 8, c0);  yr[13] = ld2<CHK>(yp, r0 + 8, c0);

    vconv2<0>(xr, yr, hA, pws, win);     // pair 0 -> buf A
    __syncthreads();

    float lsum = 0.f;

    // round 0: hpass(A) || vconv pair1 -> B || prefetch 14,15
    xr[14] = ld2<CHK>(xp, r0 + 9, c0);   yr[14] = ld2<CHK>(yp, r0 + 9, c0);
    xr[15] = ld2<CHK>(xp, r0 + 10, c0);  yr[15] = ld2<CHK>(yp, r0 + 10, c0);
    lsum += hpass2(hA, row, l, pb, win);
    vconv2<2>(xr, yr, hB, pws, win);
    __syncthreads();

    // round 1: hpass(B) || vconv pair2 -> A || prefetch 16,17
    xr[16] = ld2<CHK>(xp, r0 + 11, c0);  yr[16] = ld2<CHK>(yp, r0 + 11, c0);
    xr[17] = ld2<CHK>(xp, r0 + 12, c0);  yr[17] = ld2<CHK>(yp, r0 + 12, c0);
    lsum += hpass2(hB, row, l, pb, win);
    vconv2<4>(xr, yr, hA, pws, win);
    __syncthreads();

    // round 2: hpass(A) || vconv pair3 -> B
    lsum += hpass2(hA, row, l, pb, win);
    vconv2<6>(xr, yr, hB, pws, win);
    __syncthreads();

    // round 3: hpass(B)
    lsum += hpass2(hB, row, l, pb, win);
    return lsum;
}

__global__ __launch_bounds__(256)
void ssim_pipe_kernel(const float* __restrict__ x,
                      const float* __restrict__ y,
                      double* __restrict__ accum,
                      GWin win)
{
    __shared__ __align__(16) float hbuf[2 * BSTR];   // exactly 40960 B

    const int tid = threadIdx.x;
    // XCD-aware swizzle: consecutive logical bands share one XCD's L2.
    const int bid = blockIdx.x;
    const int L   = (bid & 7) * (NBLK / 8) + (bid >> 3);
    const int band  = L & (BANDS - 1);
    const int plane = L >> 6;
    const int r0    = band * R_OUT;
    const int c0    = tid * 2;

    const float* __restrict__ xp = x + (size_t)plane * (IMG_H * IMG_W);
    const float* __restrict__ yp = y + (size_t)plane * (IMG_H * IMG_W);

    float lsum;
    if (band >= 1 && band <= BANDS - 2)
        lsum = band_body<false>(xp, yp, r0, c0, tid, hbuf, win);
    else
        lsum = band_body<true>(xp, yp, r0, c0, tid, hbuf, win);

    // wave reduction, then one scattered global atomic per wave (no LDS)
#pragma unroll
    for (int off = 32; off; off >>= 1) lsum += __shfl_down(lsum, off);
    if ((tid & 63) == 0) {
        const int wid = L * 4 + (tid >> 6);
        atomicAdd(&accum[(wid & (NSLOT - 1)) * 8], (double)lsum);  // 64B stride
    }
}

__global__ void ssim_finalize_kernel(const double* __restrict__ accum,
                                     float* __restrict__ out)
{
    double s = 0.0;
    for (int i = 0; i < NSLOT; ++i) s += accum[i * 8];
    out[0] = (float)(s / (double)TOTAL_PIX);
}

extern "C" void kernel_launch(void* const* d_in, const int* in_sizes, int n_in,
                              void* d_out, int out_size, void* d_ws, size_t ws_size,
                              hipStream_t stream) {
    const float* x = (const float*)d_in[0];
    const float* y = (const float*)d_in[1];
    float* out = (float*)d_out;
    double* accum = (double*)d_ws;

    GWin win;
    {
        double g[11], s = 0.0;
        for (int i = 0; i < 11; ++i) {
            double d = (double)i - 5.0;
            g[i] = std::exp(-(d * d) / (2.0 * 1.5 * 1.5));
            s += g[i];
        }
        for (int i = 0; i < 11; ++i) win.g[i] = (float)(g[i] / s);
    }

    (void)hipMemsetAsync(d_ws, 0, NSLOT * 8 * sizeof(double), stream);

    ssim_pipe_kernel<<<NBLK, 256, 0, stream>>>(x, y, accum, win);
    ssim_finalize_kernel<<<1, 1, 0, stream>>>(accum, out);
}

// Round 20
// 71.071 us; speedup vs baseline: 1.6525x; 1.6525x over previous
//
#include <hip/hip_runtime.h>
#include <cmath>

// x,y: (16,3,512,512) f32. Fused separable-Gaussian SSIM, scalar mean output.
// R17 champion structure (40KB LDS, 4 blocks/CU, cross-quad row sharing with
// prefetch, XCD swizzle) with the h-pass window read narrowed from 6xb128
// (24 floats) to 10xb64 (20 floats, exact cols 8l-6..8l+13) to cut LDS-pipe
// cycles. Lane-level clamped bases + register edge masks.
constexpr int IMG_H = 512;
constexpr int IMG_W = 512;
constexpr int PLANES = 48;
constexpr int R_OUT = 8;                 // output rows per block (2 quads)
constexpr int BANDS = IMG_H / R_OUT;     // 64
constexpr int PSTR = 512;                // field-row dwords; col c at dword c
constexpr int NSLOT = 64;                // global accumulator slots (64B apart)
constexpr int NBLK = PLANES * BANDS;     // 3072 (divisible by 8 XCDs)
constexpr long long TOTAL_PIX = (long long)PLANES * IMG_H * IMG_W;

struct GWin { float g[11]; };

// XOR bank swizzle on within-field-row dword offset (bits 2..4 ^= bits 5..7).
// Preserves dword pairs (bit 1 untouched): swzd(2m+1) == swzd(2m)+1, so b64
// reads/writes at even bases stay contiguous.
__device__ __forceinline__ int swzd(int d) { return d ^ (((d >> 5) & 7) << 2); }

template<bool CHK>
__device__ __forceinline__ float2 ld2(const float* __restrict__ base, int gr, int c0) {
    if (CHK && (unsigned)gr >= (unsigned)IMG_H) return make_float2(0.f, 0.f);
    return *(const float2*)(base + (size_t)gr * IMG_W + c0);
}

// horizontal 11-tap conv + SSIM over one LDS row (5 fields), 8 cols per lane.
// w20[i] = col (8l-6)+i, read as 10 b64 at precomputed swizzled bases pd[10].
// Lane 0 zeroes cols -6..-1 (w20[0..5]); lane 63 zeroes cols 512..517
// (w20[14..19]). Output col c=8l+j uses taps w20[j+1..j+11].
__device__ __forceinline__ float hpass8(const float* __restrict__ fr0,
                                        int l, const int (&pd)[10],
                                        const GWin& win) {
    float m[5][8];
#pragma unroll
    for (int f = 0; f < 5; ++f) {
        const float* fr = fr0 + f * PSTR;
        float w20[20];
#pragma unroll
        for (int B = 0; B < 10; ++B) {
            const float2 v = *(const float2*)&fr[pd[B]];
            w20[2 * B]     = v.x;
            w20[2 * B + 1] = v.y;
        }
        if (l == 0)  { w20[0] = w20[1] = w20[2] = w20[3] = w20[4] = w20[5] = 0.f; }
        if (l == 63) { w20[14] = w20[15] = w20[16] = w20[17] = w20[18] = w20[19] = 0.f; }
#pragma unroll
        for (int j = 0; j < 8; ++j) {
            float s = 0.f;
#pragma unroll
            for (int k = 0; k < 11; ++k) s += win.g[k] * w20[j + 1 + k];
            m[f][j] = s;
        }
    }
    float ls = 0.f;
#pragma unroll
    for (int u = 0; u < 8; ++u) {
        const float mx  = m[0][u], my  = m[1][u];
        const float mxx = m[2][u], myy = m[3][u], mxy = m[4][u];
        const float mu_x_sq = mx * mx;
        const float mu_y_sq = my * my;
        const float mu_xy   = mx * my;
        const float sig_x  = mxx - mu_x_sq;
        const float sig_y  = myy - mu_y_sq;
        const float sig_xy = mxy - mu_xy;
        const float C1 = 0.01f * 0.01f;
        const float C2 = 0.03f * 0.03f;
        const float n = (2.f * mu_xy + C1) * (2.f * sig_xy + C2);
        const float d = (mu_x_sq + mu_y_sq + C1) * (sig_x + sig_y + C2);
        ls += n * __builtin_amdgcn_rcpf(d + 1e-8f);   // ~1 ulp; mean-safe
    }
    return ls;
}

// v-conv of 4 rows from 14 resident register rows; write to swizzled LDS
template<int I0>
__device__ __forceinline__ void vconv4(const float2 (&xr)[18], const float2 (&yr)[18],
                                       float* __restrict__ hb, int pws,
                                       const GWin& win) {
    float2 acc[4][5];
#pragma unroll
    for (int j = 0; j < 4; ++j)
#pragma unroll
        for (int f = 0; f < 5; ++f) acc[j][f] = make_float2(0.f, 0.f);
#pragma unroll
    for (int k = 0; k < 14; ++k) {
        const float2 xv = xr[I0 + k], yv = yr[I0 + k];
        const float2 pxx = make_float2(xv.x * xv.x, xv.y * xv.y);
        const float2 pyy = make_float2(yv.x * yv.x, yv.y * yv.y);
        const float2 pxy = make_float2(xv.x * yv.x, xv.y * yv.y);
#pragma unroll
        for (int j = 0; j < 4; ++j) {
            const int t = k - j;               // compile-time
            if (t >= 0 && t <= 10) {
                const float g = win.g[t];
                acc[j][0].x += g * xv.x;   acc[j][0].y += g * xv.y;
                acc[j][1].x += g * yv.x;   acc[j][1].y += g * yv.y;
                acc[j][2].x += g * pxx.x;  acc[j][2].y += g * pxx.y;
                acc[j][3].x += g * pyy.x;  acc[j][3].y += g * pyy.y;
                acc[j][4].x += g * pxy.x;  acc[j][4].y += g * pxy.y;
            }
        }
    }
#pragma unroll
    for (int j = 0; j < 4; ++j)
#pragma unroll
        for (int f = 0; f < 5; ++f)
            *(float2*)&hb[(j * 5 + f) * PSTR + pws] = acc[j][f];
}

template<bool CHK>
__device__ __forceinline__ float band_body(const float* __restrict__ xp,
                                           const float* __restrict__ yp,
                                           int r0, int c0, int tid,
                                           float* __restrict__ hb,
                                           const GWin& win)
{
    const int pws = swzd(2 * tid);
    const int row = tid >> 6, l = tid & 63;
    int pd[10];
#pragma unroll
    for (int B = 0; B < 10; ++B) {       // hoisted h-read b64 bases (clamped)
        int d = 8 * l - 6 + 2 * B;
        d = d < 0 ? 0 : (d > 510 ? 510 : d);
        pd[B] = swzd(d);
    }

    // rows i=0..17 <-> image rows r0-5+i. Load 0..13 now (quad 0).
    float2 xr[18], yr[18];
#pragma unroll
    for (int i = 0; i < 14; ++i) {
        xr[i] = ld2<CHK>(xp, r0 - 5 + i, c0);
        yr[i] = ld2<CHK>(yp, r0 - 5 + i, c0);
    }

    // quad 0: rows r0..r0+3 from xr[0..13]
    vconv4<0>(xr, yr, hb, pws, win);
    __syncthreads();

    // prefetch quad-1-only rows (i=14..17) under the q0 h-pass
#pragma unroll
    for (int i = 14; i < 18; ++i) {
        xr[i] = ld2<CHK>(xp, r0 - 5 + i, c0);
        yr[i] = ld2<CHK>(yp, r0 - 5 + i, c0);
    }

    float lsum = hpass8(hb + row * 5 * PSTR, l, pd, win);
    __syncthreads();                      // protect hbuf before q1 writes

    // quad 1: rows r0+4..r0+7 from xr[4..17]
    vconv4<4>(xr, yr, hb, pws, win);
    __syncthreads();

    lsum += hpass8(hb + row * 5 * PSTR, l, pd, win);
    return lsum;
}

__global__ __launch_bounds__(256)
void ssim_b64w_kernel(const float* __restrict__ x,
                      const float* __restrict__ y,
                      double* __restrict__ accum,
                      GWin win)
{
    __shared__ __align__(16) float hbuf[4 * 5 * PSTR];   // exactly 40960 B

    const int tid = threadIdx.x;
    // XCD-aware swizzle: consecutive logical bands share one XCD's L2.
    const int bid = blockIdx.x;
    const int L   = (bid & 7) * (NBLK / 8) + (bid >> 3);
    const int band  = L & (BANDS - 1);
    const int plane = L >> 6;
    const int r0    = band * R_OUT;
    const int c0    = tid * 2;

    const float* __restrict__ xp = x + (size_t)plane * (IMG_H * IMG_W);
    const float* __restrict__ yp = y + (size_t)plane * (IMG_H * IMG_W);

    float lsum;
    if (band >= 1 && band <= BANDS - 2)
        lsum = band_body<false>(xp, yp, r0, c0, tid, hbuf, win);
    else
        lsum = band_body<true>(xp, yp, r0, c0, tid, hbuf, win);

    // wave reduction, then one scattered global atomic per wave (no LDS)
#pragma unroll
    for (int off = 32; off; off >>= 1) lsum += __shfl_down(lsum, off);
    if ((tid & 63) == 0) {
        const int wid = L * 4 + (tid >> 6);
        atomicAdd(&accum[(wid & (NSLOT - 1)) * 8], (double)lsum);  // 64B stride
    }
}

__global__ void ssim_finalize_kernel(const double* __restrict__ accum,
                                     float* __restrict__ out)
{
    double s = 0.0;
    for (int i = 0; i < NSLOT; ++i) s += accum[i * 8];
    out[0] = (float)(s / (double)TOTAL_PIX);
}

extern "C" void kernel_launch(void* const* d_in, const int* in_sizes, int n_in,
                              void* d_out, int out_size, void* d_ws, size_t ws_size,
                              hipStream_t stream) {
    const float* x = (const float*)d_in[0];
    const float* y = (const float*)d_in[1];
    float* out = (float*)d_out;
    double* accum = (double*)d_ws;

    GWin win;
    {
        double g[11], s = 0.0;
        for (int i = 0; i < 11; ++i) {
            double d = (double)i - 5.0;
            g[i] = std::exp(-(d * d) / (2.0 * 1.5 * 1.5));
            s += g[i];
        }
        for (int i = 0; i < 11; ++i) win.g[i] = (float)(g[i] / s);
    }

    (void)hipMemsetAsync(d_ws, 0, NSLOT * 8 * sizeof(double), stream);

    ssim_b64w_kernel<<<NBLK, 256, 0, stream>>>(x, y, accum, win);
    ssim_finalize_kernel<<<1, 1, 0, stream>>>(accum, out);
}

// Round 21
// 63.200 us; speedup vs baseline: 1.8583x; 1.1245x over previous
//
#include <hip/hip_runtime.h>
#include <cmath>

// x,y: (16,3,512,512) f32. Fused separable-Gaussian SSIM, scalar mean output.
// R17 champion structure + sum/difference algebraic reduction: convolve only
// 4 fields {s=x+y, d=x-y, s^2, d^2}. SSIM needs just mu_x,mu_y,sig_xy and
// sig_x+sig_y, all recoverable:  4mu_xy=s~^2-d~^2,  2(mu_x^2+mu_y^2)=s~^2+d~^2,
// 4sig_xy=(css-cdd)-(s~^2-d~^2),  2(sig_x+sig_y)=(css+cdd)-(s~^2+d~^2).
// -20% v-conv/LDS/h-conv; LDS 32KB -> 5 blocks/CU. XCD swizzle, rcp div.
constexpr int IMG_H = 512;
constexpr int IMG_W = 512;
constexpr int PLANES = 48;
constexpr int R_OUT = 8;                 // output rows per block (2 quads)
constexpr int BANDS = IMG_H / R_OUT;     // 64
constexpr int PSTR = 512;                // field-row dwords; col c at dword c
constexpr int NSLOT = 64;                // global accumulator slots (64B apart)
constexpr int NBLK = PLANES * BANDS;     // 3072 (divisible by 8 XCDs)
constexpr long long TOTAL_PIX = (long long)PLANES * IMG_H * IMG_W;

struct GWin { float g[11]; };

// XOR bank swizzle on within-field-row dword offset (bits 2..4 ^= bits 5..7).
__device__ __forceinline__ int swzd(int d) { return d ^ (((d >> 5) & 7) << 2); }
__device__ __forceinline__ int swzd4(int b) { return b ^ ((b >> 3) & 7); }

template<bool CHK>
__device__ __forceinline__ float2 ld2(const float* __restrict__ base, int gr, int c0) {
    if (CHK && (unsigned)gr >= (unsigned)IMG_H) return make_float2(0.f, 0.f);
    return *(const float2*)(base + (size_t)gr * IMG_W + c0);
}

// horizontal 11-tap conv + SSIM over one LDS row (4 fields), 8 cols per lane.
// R17-verified window logic: 6xb128 covering cols 8l-8..8l+15, clamped blocks,
// register edge masks on lanes 0/63.
__device__ __forceinline__ float hpass8(const float* __restrict__ fr0,
                                        int l, const int (&pb)[6],
                                        const GWin& win) {
    float m[4][8];
#pragma unroll
    for (int f = 0; f < 4; ++f) {
        const float* fr = fr0 + f * PSTR;
        float w24[24];
#pragma unroll
        for (int B = 0; B < 6; ++B) {
            const float4 v = *(const float4*)&fr[pb[B]];
            w24[4 * B + 0] = v.x;  w24[4 * B + 1] = v.y;
            w24[4 * B + 2] = v.z;  w24[4 * B + 3] = v.w;
        }
        if (l == 0)  { w24[3] = w24[4] = w24[5] = w24[6] = w24[7] = 0.f; }
        if (l == 63) { w24[16] = w24[17] = w24[18] = w24[19] = w24[20] = 0.f; }
        // output col c = 8l+j: window cols c-5..c+5 -> w24[j+3+k]
#pragma unroll
        for (int j = 0; j < 8; ++j) {
            float s = 0.f;
#pragma unroll
            for (int k = 0; k < 11; ++k) s += win.g[k] * w24[j + 3 + k];
            m[f][j] = s;
        }
    }
    float ls = 0.f;
#pragma unroll
    for (int u = 0; u < 8; ++u) {
        const float sb  = m[0][u];        // conv(x+y)
        const float db  = m[1][u];        // conv(x-y)
        const float css = m[2][u];        // conv((x+y)^2)
        const float cdd = m[3][u];        // conv((x-y)^2)
        const float A = sb * sb;          // (mu_x+mu_y)^2
        const float B = db * db;          // (mu_x-mu_y)^2
        // 2mu_xy = (A-B)/2 ; mu_x^2+mu_y^2 = (A+B)/2
        // 2sig_xy = ((css-cdd)-(A-B))/2 ; sig_x+sig_y = ((css+cdd)-(A+B))/2
        const float C1 = 0.01f * 0.01f;
        const float C2 = 0.03f * 0.03f;
        const float n1 = 0.5f * (A - B) + C1;
        const float n2 = 0.5f * ((css - cdd) - (A - B)) + C2;
        const float d1 = 0.5f * (A + B) + C1;
        const float d2 = 0.5f * ((css + cdd) - (A + B)) + C2;
        ls += (n1 * n2) * __builtin_amdgcn_rcpf(d1 * d2 + 1e-8f);  // ~1 ulp
    }
    return ls;
}

// v-conv of 4 rows x 4 fields {s,d,ss,dd} from 14 resident register rows
template<int I0>
__device__ __forceinline__ void vconv4(const float2 (&xr)[18], const float2 (&yr)[18],
                                       float* __restrict__ hb, int pws,
                                       const GWin& win) {
    float2 acc[4][4];
#pragma unroll
    for (int j = 0; j < 4; ++j)
#pragma unroll
        for (int f = 0; f < 4; ++f) acc[j][f] = make_float2(0.f, 0.f);
#pragma unroll
    for (int k = 0; k < 14; ++k) {
        const float2 xv = xr[I0 + k], yv = yr[I0 + k];
        const float2 sv = make_float2(xv.x + yv.x, xv.y + yv.y);
        const float2 dv = make_float2(xv.x - yv.x, xv.y - yv.y);
        const float2 ssv = make_float2(sv.x * sv.x, sv.y * sv.y);
        const float2 ddv = make_float2(dv.x * dv.x, dv.y * dv.y);
#pragma unroll
        for (int j = 0; j < 4; ++j) {
            const int t = k - j;               // compile-time
            if (t >= 0 && t <= 10) {
                const float g = win.g[t];
                acc[j][0].x += g * sv.x;   acc[j][0].y += g * sv.y;
                acc[j][1].x += g * dv.x;   acc[j][1].y += g * dv.y;
                acc[j][2].x += g * ssv.x;  acc[j][2].y += g * ssv.y;
                acc[j][3].x += g * ddv.x;  acc[j][3].y += g * ddv.y;
            }
        }
    }
#pragma unroll
    for (int j = 0; j < 4; ++j)
#pragma unroll
        for (int f = 0; f < 4; ++f)
            *(float2*)&hb[(j * 4 + f) * PSTR + pws] = acc[j][f];
}

template<bool CHK>
__device__ __forceinline__ float band_body(const float* __restrict__ xp,
                                           const float* __restrict__ yp,
                                           int r0, int c0, int tid,
                                           float* __restrict__ hb,
                                           const GWin& win)
{
    const int pws = swzd(2 * tid);
    const int row = tid >> 6, l = tid & 63;
    int pb[6];
#pragma unroll
    for (int B = 0; B < 6; ++B) {        // hoisted h-read addresses (clamped)
        int blk = 2 * l - 2 + B;
        blk = blk < 0 ? 0 : (blk > 127 ? 127 : blk);
        pb[B] = 4 * swzd4(blk);
    }

    // rows i=0..17 <-> image rows r0-5+i. Load 0..13 now (quad 0).
    float2 xr[18], yr[18];
#pragma unroll
    for (int i = 0; i < 14; ++i) {
        xr[i] = ld2<CHK>(xp, r0 - 5 + i, c0);
        yr[i] = ld2<CHK>(yp, r0 - 5 + i, c0);
    }

    // quad 0: rows r0..r0+3 from xr[0..13]
    vconv4<0>(xr, yr, hb, pws, win);
    __syncthreads();

    // prefetch quad-1-only rows (i=14..17) under the q0 h-pass
#pragma unroll
    for (int i = 14; i < 18; ++i) {
        xr[i] = ld2<CHK>(xp, r0 - 5 + i, c0);
        yr[i] = ld2<CHK>(yp, r0 - 5 + i, c0);
    }

    float lsum = hpass8(hb + row * 4 * PSTR, l, pb, win);
    __syncthreads();                      // protect hbuf before q1 writes

    // quad 1: rows r0+4..r0+7 from xr[4..17]
    vconv4<4>(xr, yr, hb, pws, win);
    __syncthreads();

    lsum += hpass8(hb + row * 4 * PSTR, l, pb, win);
    return lsum;
}

__global__ __launch_bounds__(256)
void ssim_sd_kernel(const float* __restrict__ x,
                    const float* __restrict__ y,
                    double* __restrict__ accum,
                    GWin win)
{
    __shared__ __align__(16) float hbuf[4 * 4 * PSTR];   // exactly 32768 B

    const int tid = threadIdx.x;
    // XCD-aware swizzle: consecutive logical bands share one XCD's L2.
    const int bid = blockIdx.x;
    const int L   = (bid & 7) * (NBLK / 8) + (bid >> 3);
    const int band  = L & (BANDS - 1);
    const int plane = L >> 6;
    const int r0    = band * R_OUT;
    const int c0    = tid * 2;

    const float* __restrict__ xp = x + (size_t)plane * (IMG_H * IMG_W);
    const float* __restrict__ yp = y + (size_t)plane * (IMG_H * IMG_W);

    float lsum;
    if (band >= 1 && band <= BANDS - 2)
        lsum = band_body<false>(xp, yp, r0, c0, tid, hbuf, win);
    else
        lsum = band_body<true>(xp, yp, r0, c0, tid, hbuf, win);

    // wave reduction, then one scattered global atomic per wave (no LDS)
#pragma unroll
    for (int off = 32; off; off >>= 1) lsum += __shfl_down(lsum, off);
    if ((tid & 63) == 0) {
        const int wid = L * 4 + (tid >> 6);
        atomicAdd(&accum[(wid & (NSLOT - 1)) * 8], (double)lsum);  // 64B stride
    }
}

__global__ void ssim_finalize_kernel(const double* __restrict__ accum,
                                     float* __restrict__ out)
{
    double s = 0.0;
    for (int i = 0; i < NSLOT; ++i) s += accum[i * 8];
    out[0] = (float)(s / (double)TOTAL_PIX);
}

extern "C" void kernel_launch(void* const* d_in, const int* in_sizes, int n_in,
                              void* d_out, int out_size, void* d_ws, size_t ws_size,
                              hipStream_t stream) {
    const float* x = (const float*)d_in[0];
    const float* y = (const float*)d_in[1];
    float* out = (float*)d_out;
    double* accum = (double*)d_ws;

    GWin win;
    {
        double g[11], s = 0.0;
        for (int i = 0; i < 11; ++i) {
            double d = (double)i - 5.0;
            g[i] = std::exp(-(d * d) / (2.0 * 1.5 * 1.5));
            s += g[i];
        }
        for (int i = 0; i < 11; ++i) win.g[i] = (float)(g[i] / s);
    }

    (void)hipMemsetAsync(d_ws, 0, NSLOT * 8 * sizeof(double), stream);

    ssim_sd_kernel<<<NBLK, 256, 0, stream>>>(x, y, accum, win);
    ssim_finalize_kernel<<<1, 1, 0, stream>>>(accum, out);
}

// Round 22
// 60.299 us; speedup vs baseline: 1.9477x; 1.0481x over previous
//
#include <hip/hip_runtime.h>
#include <cmath>

// x,y: (16,3,512,512) f32. Fused separable-Gaussian SSIM, scalar mean output.
// R21 champion main kernel (sum/diff 4-field basis, 32KB LDS = 5 blocks/CU,
// cross-quad row sharing + prefetch, XOR bank swizzle, XCD block swizzle,
// rcp div) + parallel 64-thread finalize (was a 10us serial pointer-walk).
constexpr int IMG_H = 512;
constexpr int IMG_W = 512;
constexpr int PLANES = 48;
constexpr int R_OUT = 8;                 // output rows per block (2 quads)
constexpr int BANDS = IMG_H / R_OUT;     // 64
constexpr int PSTR = 512;                // field-row dwords; col c at dword c
constexpr int NSLOT = 64;                // global accumulator slots (64B apart)
constexpr int NBLK = PLANES * BANDS;     // 3072 (divisible by 8 XCDs)
constexpr long long TOTAL_PIX = (long long)PLANES * IMG_H * IMG_W;

struct GWin { float g[11]; };

// XOR bank swizzle on within-field-row dword offset (bits 2..4 ^= bits 5..7).
__device__ __forceinline__ int swzd(int d) { return d ^ (((d >> 5) & 7) << 2); }
__device__ __forceinline__ int swzd4(int b) { return b ^ ((b >> 3) & 7); }

template<bool CHK>
__device__ __forceinline__ float2 ld2(const float* __restrict__ base, int gr, int c0) {
    if (CHK && (unsigned)gr >= (unsigned)IMG_H) return make_float2(0.f, 0.f);
    return *(const float2*)(base + (size_t)gr * IMG_W + c0);
}

// horizontal 11-tap conv + SSIM over one LDS row (4 fields), 8 cols per lane.
__device__ __forceinline__ float hpass8(const float* __restrict__ fr0,
                                        int l, const int (&pb)[6],
                                        const GWin& win) {
    float m[4][8];
#pragma unroll
    for (int f = 0; f < 4; ++f) {
        const float* fr = fr0 + f * PSTR;
        float w24[24];
#pragma unroll
        for (int B = 0; B < 6; ++B) {
            const float4 v = *(const float4*)&fr[pb[B]];
            w24[4 * B + 0] = v.x;  w24[4 * B + 1] = v.y;
            w24[4 * B + 2] = v.z;  w24[4 * B + 3] = v.w;
        }
        if (l == 0)  { w24[3] = w24[4] = w24[5] = w24[6] = w24[7] = 0.f; }
        if (l == 63) { w24[16] = w24[17] = w24[18] = w24[19] = w24[20] = 0.f; }
        // output col c = 8l+j: window cols c-5..c+5 -> w24[j+3+k]
#pragma unroll
        for (int j = 0; j < 8; ++j) {
            float s = 0.f;
#pragma unroll
            for (int k = 0; k < 11; ++k) s += win.g[k] * w24[j + 3 + k];
            m[f][j] = s;
        }
    }
    float ls = 0.f;
#pragma unroll
    for (int u = 0; u < 8; ++u) {
        const float sb  = m[0][u];        // conv(x+y)
        const float db  = m[1][u];        // conv(x-y)
        const float css = m[2][u];        // conv((x+y)^2)
        const float cdd = m[3][u];        // conv((x-y)^2)
        const float A = sb * sb;
        const float B = db * db;
        const float C1 = 0.01f * 0.01f;
        const float C2 = 0.03f * 0.03f;
        const float n1 = 0.5f * (A - B) + C1;
        const float n2 = 0.5f * ((css - cdd) - (A - B)) + C2;
        const float d1 = 0.5f * (A + B) + C1;
        const float d2 = 0.5f * ((css + cdd) - (A + B)) + C2;
        ls += (n1 * n2) * __builtin_amdgcn_rcpf(d1 * d2 + 1e-8f);  // ~1 ulp
    }
    return ls;
}

// v-conv of 4 rows x 4 fields {s,d,ss,dd} from 14 resident register rows
template<int I0>
__device__ __forceinline__ void vconv4(const float2 (&xr)[18], const float2 (&yr)[18],
                                       float* __restrict__ hb, int pws,
                                       const GWin& win) {
    float2 acc[4][4];
#pragma unroll
    for (int j = 0; j < 4; ++j)
#pragma unroll
        for (int f = 0; f < 4; ++f) acc[j][f] = make_float2(0.f, 0.f);
#pragma unroll
    for (int k = 0; k < 14; ++k) {
        const float2 xv = xr[I0 + k], yv = yr[I0 + k];
        const float2 sv = make_float2(xv.x + yv.x, xv.y + yv.y);
        const float2 dv = make_float2(xv.x - yv.x, xv.y - yv.y);
        const float2 ssv = make_float2(sv.x * sv.x, sv.y * sv.y);
        const float2 ddv = make_float2(dv.x * dv.x, dv.y * dv.y);
#pragma unroll
        for (int j = 0; j < 4; ++j) {
            const int t = k - j;               // compile-time
            if (t >= 0 && t <= 10) {
                const float g = win.g[t];
                acc[j][0].x += g * sv.x;   acc[j][0].y += g * sv.y;
                acc[j][1].x += g * dv.x;   acc[j][1].y += g * dv.y;
                acc[j][2].x += g * ssv.x;  acc[j][2].y += g * ssv.y;
                acc[j][3].x += g * ddv.x;  acc[j][3].y += g * ddv.y;
            }
        }
    }
#pragma unroll
    for (int j = 0; j < 4; ++j)
#pragma unroll
        for (int f = 0; f < 4; ++f)
            *(float2*)&hb[(j * 4 + f) * PSTR + pws] = acc[j][f];
}

template<bool CHK>
__device__ __forceinline__ float band_body(const float* __restrict__ xp,
                                           const float* __restrict__ yp,
                                           int r0, int c0, int tid,
                                           float* __restrict__ hb,
                                           const GWin& win)
{
    const int pws = swzd(2 * tid);
    const int row = tid >> 6, l = tid & 63;
    int pb[6];
#pragma unroll
    for (int B = 0; B < 6; ++B) {        // hoisted h-read addresses (clamped)
        int blk = 2 * l - 2 + B;
        blk = blk < 0 ? 0 : (blk > 127 ? 127 : blk);
        pb[B] = 4 * swzd4(blk);
    }

    // rows i=0..17 <-> image rows r0-5+i. Load 0..13 now (quad 0).
    float2 xr[18], yr[18];
#pragma unroll
    for (int i = 0; i < 14; ++i) {
        xr[i] = ld2<CHK>(xp, r0 - 5 + i, c0);
        yr[i] = ld2<CHK>(yp, r0 - 5 + i, c0);
    }

    // quad 0: rows r0..r0+3 from xr[0..13]
    vconv4<0>(xr, yr, hb, pws, win);
    __syncthreads();

    // prefetch quad-1-only rows (i=14..17) under the q0 h-pass
#pragma unroll
    for (int i = 14; i < 18; ++i) {
        xr[i] = ld2<CHK>(xp, r0 - 5 + i, c0);
        yr[i] = ld2<CHK>(yp, r0 - 5 + i, c0);
    }

    float lsum = hpass8(hb + row * 4 * PSTR, l, pb, win);
    __syncthreads();                      // protect hbuf before q1 writes

    // quad 1: rows r0+4..r0+7 from xr[4..17]
    vconv4<4>(xr, yr, hb, pws, win);
    __syncthreads();

    lsum += hpass8(hb + row * 4 * PSTR, l, pb, win);
    return lsum;
}

__global__ __launch_bounds__(256)
void ssim_sd_kernel(const float* __restrict__ x,
                    const float* __restrict__ y,
                    double* __restrict__ accum,
                    GWin win)
{
    __shared__ __align__(16) float hbuf[4 * 4 * PSTR];   // exactly 32768 B

    const int tid = threadIdx.x;
    // XCD-aware swizzle: consecutive logical bands share one XCD's L2.
    const int bid = blockIdx.x;
    const int L   = (bid & 7) * (NBLK / 8) + (bid >> 3);
    const int band  = L & (BANDS - 1);
    const int plane = L >> 6;
    const int r0    = band * R_OUT;
    const int c0    = tid * 2;

    const float* __restrict__ xp = x + (size_t)plane * (IMG_H * IMG_W);
    const float* __restrict__ yp = y + (size_t)plane * (IMG_H * IMG_W);

    float lsum;
    if (band >= 1 && band <= BANDS - 2)
        lsum = band_body<false>(xp, yp, r0, c0, tid, hbuf, win);
    else
        lsum = band_body<true>(xp, yp, r0, c0, tid, hbuf, win);

    // wave reduction, then one scattered global atomic per wave (no LDS)
#pragma unroll
    for (int off = 32; off; off >>= 1) lsum += __shfl_down(lsum, off);
    if ((tid & 63) == 0) {
        const int wid = L * 4 + (tid >> 6);
        atomicAdd(&accum[(wid & (NSLOT - 1)) * 8], (double)lsum);  // 64B stride
    }
}

// Parallel finalize: 64 lanes each load one slot (concurrent, ~1 latency),
// f64 shuffle butterfly, lane 0 writes the mean. (Old 1-thread version was a
// ~10us serial L2 pointer-walk.)
__global__ __launch_bounds__(64)
void ssim_finalize_kernel(const double* __restrict__ accum,
                          float* __restrict__ out)
{
    const int l = threadIdx.x;
    double s = accum[l * 8];
#pragma unroll
    for (int off = 32; off; off >>= 1) s += __shfl_down(s, off);
    if (l == 0) out[0] = (float)(s / (double)TOTAL_PIX);
}

extern "C" void kernel_launch(void* const* d_in, const int* in_sizes, int n_in,
                              void* d_out, int out_size, void* d_ws, size_t ws_size,
                              hipStream_t stream) {
    const float* x = (const float*)d_in[0];
    const float* y = (const float*)d_in[1];
    float* out = (float*)d_out;
    double* accum = (double*)d_ws;

    GWin win;
    {
        double g[11], s = 0.0;
        for (int i = 0; i < 11; ++i) {
            double d = (double)i - 5.0;
            g[i] = std::exp(-(d * d) / (2.0 * 1.5 * 1.5));
            s += g[i];
        }
        for (int i = 0; i < 11; ++i) win.g[i] = (float)(g[i] / s);
    }

    (void)hipMemsetAsync(d_ws, 0, NSLOT * 8 * sizeof(double), stream);

    ssim_sd_kernel<<<NBLK, 256, 0, stream>>>(x, y, accum, win);
    ssim_finalize_kernel<<<1, 64, 0, stream>>>(accum, out);
}